// Round 5
// baseline (236.166 us; speedup 1.0000x reference)
//
#include <hip/hip_runtime.h>
#include <hip/hip_cooperative_groups.h>

namespace cg = cooperative_groups;

#define F 128
#define TA 12         // atoms per block in MLP phase (512 * 12 = 6144)
#define NSEG 64
#define CAP 256       // max atoms per segment staged in LDS (seg avg ~96)
#define NBLK 512      // 64 segs x 8 chunks; exactly 2 blocks/CU -> co-resident
#define KE 14.3996f

__device__ __forceinline__ float silu_f(float x) {
    return x / (1.0f + expf(-x));
}
__device__ __forceinline__ float softplus_f(float x) {
    return fmaxf(x, 0.0f) + log1pf(expf(-fabsf(x)));
}

// ---------------- pair-energy inner loop ----------------
template <bool USE_LDS>
__device__ float seg_energy_loop(int start, unsigned ns, unsigned chunk, float mn,
    float inv_s2s, float inv_sig,
    const float* __restrict__ pos, const float* __restrict__ qr,
    const float* __restrict__ c6a, const float* __restrict__ rva,
    const float* __restrict__ mua,
    const float* spos, const float* smu,
    const float* sq, const float* sc, const float* sr)
{
    float e = 0.0f;
    unsigned total = ns * ns;
    unsigned stride = 8u * 256u;          // 8 chunks x 256 threads
    unsigned p = chunk * 256u + threadIdx.x;
    if (p >= total) return 0.0f;
    unsigned i = p / ns;
    unsigned j = p - i * ns;
    unsigned di = stride / ns;
    unsigned dj = stride - di * ns;
    while (i < ns) {
        if (i != j) {
            float xi, yi, zi, qi, ci, ri, mxi, myi, mzi;
            float xj, yj, zj, qj, cj, rj, mxj, myj, mzj;
            if constexpr (USE_LDS) {
                xi = spos[3 * i]; yi = spos[3 * i + 1]; zi = spos[3 * i + 2];
                qi = sq[i]; ci = sc[i]; ri = sr[i];
                mxi = smu[3 * i]; myi = smu[3 * i + 1]; mzi = smu[3 * i + 2];
                xj = spos[3 * j]; yj = spos[3 * j + 1]; zj = spos[3 * j + 2];
                qj = sq[j]; cj = sc[j]; rj = sr[j];
                mxj = smu[3 * j]; myj = smu[3 * j + 1]; mzj = smu[3 * j + 2];
            } else {
                int gi = start + (int)i, gj = start + (int)j;
                xi = pos[gi * 3]; yi = pos[gi * 3 + 1]; zi = pos[gi * 3 + 2];
                qi = qr[gi] - mn; ci = c6a[gi]; ri = rva[gi];
                mxi = mua[gi * 3]; myi = mua[gi * 3 + 1]; mzi = mua[gi * 3 + 2];
                xj = pos[gj * 3]; yj = pos[gj * 3 + 1]; zj = pos[gj * 3 + 2];
                qj = qr[gj] - mn; cj = c6a[gj]; rj = rva[gj];
                mxj = mua[gj * 3]; myj = mua[gj * 3 + 1]; mzj = mua[gj * 3 + 2];
            }
            float dx = xi - xj, dy = yi - yj, dz = zi - zj;
            float d2 = dx * dx + dy * dy + dz * dz;
            float dist = sqrtf(d2 + 1e-8f);
            float inv = 1.0f / dist;
            // shielded Coulomb
            e += 0.5f * KE * qi * qj * inv * erff(dist * inv_s2s);
            // damped London dispersion: rv_ij^6 == (rv_i*rv_j)^3
            float c6ij = sqrtf(ci * cj);
            float rr = ri * rj;
            float damp = d2 * d2 * d2 + rr * rr * rr;
            e -= 0.5f * c6ij / damp;
            // dipole-dipole
            float nx = dx * inv, ny = dy * inv, nz = dz * inv;
            float mdm = mxi * mxj + myi * myj + mzi * mzj;
            float a1 = mxi * nx + myi * ny + mzi * nz;
            float a2 = mxj * nx + myj * ny + mzj * nz;
            float er = erff(dist * inv_sig);
            float rad = inv * inv * inv * er * er * er;
            e += 0.5f * KE * (mdm - 3.0f * a1 * a2) * rad;
        }
        i += di; j += dj;
        if (j >= ns) { j -= ns; ++i; }
    }
    return e;
}

// ---------------- single fused cooperative kernel ----------------
// Phase A: MLPs (q, c6, rv) + mu for TA atoms/block; block 0 also does seg scan + ticket init.
// grid.sync()
// Phase B: pair energy per (seg, chunk); last-finishing block reduces partials -> d_out.
__global__ __launch_bounds__(256, 2) void fused_kernel(
    const float* __restrict__ h0, const float* __restrict__ h1,
    const float* __restrict__ pos, const int* __restrict__ batch,
    const float* __restrict__ q_w1, const float* __restrict__ q_b1, const float* __restrict__ q_w2,
    const float* __restrict__ sigma_p,
    const float* __restrict__ vdw_w1, const float* __restrict__ vdw_b1,
    const float* __restrict__ vdw_w2, const float* __restrict__ vdw_b2,
    const float* __restrict__ mu_w,
    float* __restrict__ q_raw, float* __restrict__ c6o, float* __restrict__ rvo,
    float* __restrict__ muo, int* __restrict__ seg_start, int* __restrict__ seg_cnt,
    float* __restrict__ pairpart, int* __restrict__ ticket,
    float* __restrict__ out, int N)
{
    __shared__ float h0s[TA][F];                       // 6 KB (phase A)
    __shared__ float spos[3 * CAP], smu[3 * CAP];      // 6 KB (phase B)
    __shared__ float sq[CAP], sc[CAP], sr[CAP];        // 3 KB (phase B)
    __shared__ float red[4];
    __shared__ float s_mean;
    __shared__ int   s_last;

    const int tid = threadIdx.x;
    const int bid = blockIdx.x;

    // ================= Phase A: MLPs =================
    {
        const int m  = tid >> 7;              // wave-uniform: waves 0,1 -> q; 2,3 -> vdw
        const int hq = tid & 31;
        const int as = (tid >> 5) & 3;
        const int base = bid * TA;

        // stage h0 tile: TA x 128 floats = TA*32 float4
        {
            const float4* src = (const float4*)(h0 + (size_t)base * F);
            float4* dst = (float4*)&h0s[0][0];
            for (int idx = tid; idx < TA * 32; idx += 256) {
                int a = idx >> 5;
                dst[idx] = (base + a < N) ? src[idx] : make_float4(0.f, 0.f, 0.f, 0.f);
            }
        }
        __syncthreads();

        // layer 1: atoms {as, as+4, as+8}, hidden units 4hq..4hq+3
        const float4* __restrict__ W1v = (const float4*)(m ? vdw_w1 : q_w1);
        float acc[3][4];
        #pragma unroll
        for (int k = 0; k < 3; ++k)
            #pragma unroll
            for (int j = 0; j < 4; ++j) acc[k][j] = 0.0f;

        #pragma unroll 4
        for (int f = 0; f < F; ++f) {
            float4 w = W1v[f * 32 + hq];
            #pragma unroll
            for (int k = 0; k < 3; ++k) {
                float hv = h0s[as + 4 * k][f];
                acc[k][0] = fmaf(hv, w.x, acc[k][0]);
                acc[k][1] = fmaf(hv, w.y, acc[k][1]);
                acc[k][2] = fmaf(hv, w.z, acc[k][2]);
                acc[k][3] = fmaf(hv, w.w, acc[k][3]);
            }
        }

        // activation + layer 2 + 32-lane reduction
        if (m == 0) {
            float4 b  = ((const float4*)q_b1)[hq];
            float4 w2 = ((const float4*)q_w2)[hq];
            float part[3];
            #pragma unroll
            for (int k = 0; k < 3; ++k) {
                part[k] = silu_f(acc[k][0] + b.x) * w2.x
                        + silu_f(acc[k][1] + b.y) * w2.y
                        + silu_f(acc[k][2] + b.z) * w2.z
                        + silu_f(acc[k][3] + b.w) * w2.w;
            }
            #pragma unroll
            for (int off = 16; off > 0; off >>= 1)
                #pragma unroll
                for (int k = 0; k < 3; ++k)
                    part[k] += __shfl_xor(part[k], off, 64);
            if (hq == 0) {
                #pragma unroll
                for (int k = 0; k < 3; ++k) {
                    int n = base + as + 4 * k;
                    if (n < N) q_raw[n] = part[k];
                }
            }
        } else {
            float4 b  = ((const float4*)vdw_b1)[hq];
            float4 wA = ((const float4*)vdw_w2)[2 * hq];
            float4 wB = ((const float4*)vdw_w2)[2 * hq + 1];
            float pc[3], pr[3];
            #pragma unroll
            for (int k = 0; k < 3; ++k) {
                float s0 = silu_f(acc[k][0] + b.x);
                float s1 = silu_f(acc[k][1] + b.y);
                float s2 = silu_f(acc[k][2] + b.z);
                float s3 = silu_f(acc[k][3] + b.w);
                pc[k] = s0 * wA.x + s1 * wA.z + s2 * wB.x + s3 * wB.z;
                pr[k] = s0 * wA.y + s1 * wA.w + s2 * wB.y + s3 * wB.w;
            }
            #pragma unroll
            for (int off = 16; off > 0; off >>= 1)
                #pragma unroll
                for (int k = 0; k < 3; ++k) {
                    pc[k] += __shfl_xor(pc[k], off, 64);
                    pr[k] += __shfl_xor(pr[k], off, 64);
                }
            if (hq == 0) {
                float b2c = vdw_b2[0], b2r = vdw_b2[1];
                #pragma unroll
                for (int k = 0; k < 3; ++k) {
                    int n = base + as + 4 * k;
                    if (n < N) {
                        c6o[n] = softplus_f(pc[k] + b2c);
                        rvo[n] = softplus_f(pr[k] + b2r);
                    }
                }
            }
        }

        // mu: wave w handles atoms base + 3w + {0,1,2}
        {
            int lane = tid & 63, wid = tid >> 6;
            float2 wm = ((const float2*)mu_w)[lane];
            #pragma unroll
            for (int r = 0; r < 3; ++r) {
                int n = base + wid * 3 + r;
                if (n < N) {                              // wave-uniform
                    const float2* row = (const float2*)(h1 + (size_t)n * 3 * F);
                    float2 v0 = row[lane], v1 = row[64 + lane], v2 = row[128 + lane];
                    float p0 = v0.x * wm.x + v0.y * wm.y;
                    float p1 = v1.x * wm.x + v1.y * wm.y;
                    float p2 = v2.x * wm.x + v2.y * wm.y;
                    #pragma unroll
                    for (int off = 1; off < 64; off <<= 1) {
                        p0 += __shfl_xor(p0, off, 64);
                        p1 += __shfl_xor(p1, off, 64);
                        p2 += __shfl_xor(p2, off, 64);
                    }
                    if (lane == 0) {
                        muo[n * 3 + 0] = p0;
                        muo[n * 3 + 1] = p1;
                        muo[n * 3 + 2] = p2;
                    }
                }
            }
        }

        // block 0: segment scan (overlaps other blocks' MLP) + ticket init
        if (bid == 0) {
            if (tid < NSEG) {
                int s = tid;
                int lo = 0, hi = N;
                while (lo < hi) { int mid = (lo + hi) >> 1; if (batch[mid] < s) lo = mid + 1; else hi = mid; }
                int lo2 = lo, hi2 = N;
                while (lo2 < hi2) { int mid = (lo2 + hi2) >> 1; if (batch[mid] < s + 1) lo2 = mid + 1; else hi2 = mid; }
                seg_start[s] = lo;
                seg_cnt[s]   = lo2 - lo;
            } else if (tid == 64) {
                atomicExch(ticket, 0);                    // ws is poisoned each launch
            }
        }
    }

    // ================= grid-wide barrier (cross-XCD visibility) =================
    __threadfence();
    cg::this_grid().sync();
    __threadfence();

    // ================= Phase B: pair energy =================
    int s = bid & (NSEG - 1);
    unsigned chunk = (unsigned)bid >> 6;
    int start = seg_start[s];
    int ns = seg_cnt[s];
    float e = 0.0f;
    if (ns >= 2) {
        float sig = sigma_p[0];
        float inv_s2s = 1.0f / (1.41421356237f * sig);
        float inv_sig = 1.0f / sig;
        bool use_lds = (ns <= CAP);                       // block-uniform
        float mn = 0.0f;
        if (use_lds) {
            for (int jj = tid; jj < 3 * ns; jj += 256) {
                spos[jj] = pos[3 * start + jj];
                smu[jj]  = muo[3 * start + jj];
            }
            for (int jj = tid; jj < ns; jj += 256) {
                sq[jj] = q_raw[start + jj];
                sc[jj] = c6o[start + jj];
                sr[jj] = rvo[start + jj];
            }
            __syncthreads();
            float ms = 0.0f;
            for (int jj = tid; jj < ns; jj += 256) ms += sq[jj];
            #pragma unroll
            for (int off = 32; off > 0; off >>= 1) ms += __shfl_xor(ms, off, 64);
            if ((tid & 63) == 0) red[tid >> 6] = ms;
            __syncthreads();
            if (tid == 0) s_mean = (red[0] + red[1] + red[2] + red[3]) / (float)ns;
            __syncthreads();
            float m = s_mean;
            for (int jj = tid; jj < ns; jj += 256) sq[jj] -= m;
            __syncthreads();
            e = seg_energy_loop<true >(start, (unsigned)ns, chunk, mn, inv_s2s, inv_sig,
                                       pos, q_raw, c6o, rvo, muo, spos, smu, sq, sc, sr);
        } else {
            float ms = 0.0f;
            for (int jj = tid; jj < ns; jj += 256) ms += q_raw[start + jj];
            #pragma unroll
            for (int off = 32; off > 0; off >>= 1) ms += __shfl_xor(ms, off, 64);
            if ((tid & 63) == 0) red[tid >> 6] = ms;
            __syncthreads();
            if (tid == 0) s_mean = (red[0] + red[1] + red[2] + red[3]) / (float)ns;
            __syncthreads();
            mn = s_mean;
            e = seg_energy_loop<false>(start, (unsigned)ns, chunk, mn, inv_s2s, inv_sig,
                                       pos, q_raw, c6o, rvo, muo, spos, smu, sq, sc, sr);
        }
    }

    // block reduction -> one partial per block
    #pragma unroll
    for (int off = 32; off > 0; off >>= 1) e += __shfl_xor(e, off, 64);
    __shared__ float wsum[4];
    if ((tid & 63) == 0) wsum[tid >> 6] = e;
    __syncthreads();
    if (tid == 0) {
        pairpart[bid] = wsum[0] + wsum[1] + wsum[2] + wsum[3];
        __threadfence();                                  // release partial
        int t = atomicAdd(ticket, 1);
        s_last = (t == gridDim.x - 1) ? 1 : 0;
    }
    __syncthreads();

    // last-finishing block: reduce all partials -> d_out
    if (s_last) {
        __threadfence();                                  // acquire others' partials
        float f = 0.0f;
        for (int i = tid; i < NBLK; i += 256) f += pairpart[i];
        #pragma unroll
        for (int off = 32; off > 0; off >>= 1) f += __shfl_xor(f, off, 64);
        if ((tid & 63) == 0) red[tid >> 6] = f;
        __syncthreads();
        if (tid == 0) out[0] = red[0] + red[1] + red[2] + red[3];
    }
}

extern "C" void kernel_launch(void* const* d_in, const int* in_sizes, int n_in,
                              void* d_out, int out_size, void* d_ws, size_t ws_size,
                              hipStream_t stream) {
    const float* h0     = (const float*)d_in[0];
    const float* h1     = (const float*)d_in[1];
    const float* pos    = (const float*)d_in[2];
    const int*   batch  = (const int*)d_in[3];
    const float* q_w1   = (const float*)d_in[4];
    const float* q_b1   = (const float*)d_in[5];
    const float* q_w2   = (const float*)d_in[6];
    const float* sigma  = (const float*)d_in[7];
    const float* vdw_w1 = (const float*)d_in[8];
    const float* vdw_b1 = (const float*)d_in[9];
    const float* vdw_w2 = (const float*)d_in[10];
    const float* vdw_b2 = (const float*)d_in[11];
    const float* mu_w   = (const float*)d_in[12];

    int N = in_sizes[0] / F;

    float* ws     = (float*)d_ws;
    float* q_raw  = ws;
    float* c6     = ws + (size_t)N;
    float* rv     = ws + (size_t)2 * N;
    float* mu     = ws + (size_t)3 * N;          // 3N floats
    int*   sstart = (int*)(ws + (size_t)6 * N);  // 64
    int*   scnt   = sstart + NSEG;               // 64
    float* ppart  = (float*)(scnt + NSEG);       // NBLK
    int*   ticket = (int*)(ppart + NBLK);        // 1
    float* out    = (float*)d_out;

    void* args[] = {
        (void*)&h0, (void*)&h1, (void*)&pos, (void*)&batch,
        (void*)&q_w1, (void*)&q_b1, (void*)&q_w2, (void*)&sigma,
        (void*)&vdw_w1, (void*)&vdw_b1, (void*)&vdw_w2, (void*)&vdw_b2,
        (void*)&mu_w,
        (void*)&q_raw, (void*)&c6, (void*)&rv, (void*)&mu,
        (void*)&sstart, (void*)&scnt, (void*)&ppart, (void*)&ticket,
        (void*)&out, (void*)&N
    };
    hipLaunchCooperativeKernel((const void*)fused_kernel, dim3(NBLK), dim3(256),
                               args, 0, stream);
}

// Round 6
// 117.529 us; speedup vs baseline: 2.0094x; 2.0094x over previous
//
#include <hip/hip_runtime.h>

#define F 128
#define TA 8          // atoms per mlp block
#define NSEG 64
#define CAP 256       // max atoms per segment staged in LDS (seg avg ~96)
#define SPLIT 8       // blocks per segment in pair kernel
#define NPAIRBLK (NSEG * SPLIT)
#define KE 14.3996f

__device__ __forceinline__ float silu_f(float x) {
    return x / (1.0f + expf(-x));
}
__device__ __forceinline__ float softplus_f(float x) {
    return fmaxf(x, 0.0f) + log1pf(expf(-fabsf(x)));
}

// ---------------- Kernel 1: per-atom MLPs (q, c6, rv) + mu + seg scan + ticket init ----------------
// 256 threads. m=tid>>7 picks MLP (0=q, 1=vdw). hq=tid&31 owns hidden units 4hq..4hq+3.
// as=(tid>>5)&3 owns atoms {as, as+4}. No atomics (ticket init is a plain store).
__global__ __launch_bounds__(256) void mlp_kernel(
    const float* __restrict__ h0, const float* __restrict__ h1,
    const int* __restrict__ batch,
    const float* __restrict__ q_w1, const float* __restrict__ q_b1, const float* __restrict__ q_w2,
    const float* __restrict__ vdw_w1, const float* __restrict__ vdw_b1,
    const float* __restrict__ vdw_w2, const float* __restrict__ vdw_b2,
    const float* __restrict__ mu_w,
    float* __restrict__ q_raw, float* __restrict__ c6o, float* __restrict__ rvo,
    float* __restrict__ muo, int* __restrict__ seg_start, int* __restrict__ seg_cnt,
    int* __restrict__ ticket, int N)
{
    __shared__ float h0s[TA][F];          // 4 KB
    const int tid = threadIdx.x;
    const int m  = tid >> 7;              // wave-uniform (waves 0,1 -> q; 2,3 -> vdw)
    const int hq = tid & 31;
    const int as = (tid >> 5) & 3;
    const int base = blockIdx.x * TA;

    // ---- stage h0 tile: 8 atoms x 128 floats = 256 float4, one per thread ----
    {
        const float4* src = (const float4*)(h0 + (size_t)base * F);
        int a = tid >> 5;
        ((float4*)&h0s[0][0])[tid] =
            (base + a < N) ? src[tid] : make_float4(0.f, 0.f, 0.f, 0.f);
    }
    __syncthreads();

    // ---- layer 1: acc[k][j] = sum_f h0[atom][f] * W1[f][4hq+j], atoms {as, as+4} ----
    // 4-f groups: 4 float4 weight loads + 2 ds_read_b128 + 32 FMA.
    const float4* __restrict__ W1v = (const float4*)(m ? vdw_w1 : q_w1);
    float acc[2][4];
    #pragma unroll
    for (int k = 0; k < 2; ++k)
        #pragma unroll
        for (int j = 0; j < 4; ++j) acc[k][j] = 0.0f;

    for (int f0 = 0; f0 < F; f0 += 4) {
        float4 wv[4];
        #pragma unroll
        for (int c = 0; c < 4; ++c) wv[c] = W1v[(f0 + c) * 32 + hq];
        float4 hA = *(const float4*)&h0s[as][f0];        // wave-broadcast (2 addrs/wave)
        float4 hB = *(const float4*)&h0s[as + 4][f0];
        float ha[4] = {hA.x, hA.y, hA.z, hA.w};
        float hb[4] = {hB.x, hB.y, hB.z, hB.w};
        #pragma unroll
        for (int c = 0; c < 4; ++c) {
            float wc[4] = {wv[c].x, wv[c].y, wv[c].z, wv[c].w};
            #pragma unroll
            for (int j = 0; j < 4; ++j) {
                acc[0][j] = fmaf(ha[c], wc[j], acc[0][j]);
                acc[1][j] = fmaf(hb[c], wc[j], acc[1][j]);
            }
        }
    }

    // ---- activation + layer 2 + 32-lane reduction ----
    if (m == 0) {
        float4 b  = ((const float4*)q_b1)[hq];
        float4 w2 = ((const float4*)q_w2)[hq];
        float part[2];
        #pragma unroll
        for (int k = 0; k < 2; ++k) {
            part[k] = silu_f(acc[k][0] + b.x) * w2.x
                    + silu_f(acc[k][1] + b.y) * w2.y
                    + silu_f(acc[k][2] + b.z) * w2.z
                    + silu_f(acc[k][3] + b.w) * w2.w;
        }
        #pragma unroll
        for (int off = 16; off > 0; off >>= 1)
            #pragma unroll
            for (int k = 0; k < 2; ++k)
                part[k] += __shfl_xor(part[k], off, 64);
        if (hq == 0) {
            #pragma unroll
            for (int k = 0; k < 2; ++k) {
                int n = base + as + 4 * k;
                if (n < N) q_raw[n] = part[k];
            }
        }
    } else {
        float4 b  = ((const float4*)vdw_b1)[hq];
        float4 wA = ((const float4*)vdw_w2)[2 * hq];      // (c6w,rvw) for units 4hq,4hq+1
        float4 wB = ((const float4*)vdw_w2)[2 * hq + 1];  // units 4hq+2,4hq+3
        float pc[2], pr[2];
        #pragma unroll
        for (int k = 0; k < 2; ++k) {
            float s0 = silu_f(acc[k][0] + b.x);
            float s1 = silu_f(acc[k][1] + b.y);
            float s2 = silu_f(acc[k][2] + b.z);
            float s3 = silu_f(acc[k][3] + b.w);
            pc[k] = s0 * wA.x + s1 * wA.z + s2 * wB.x + s3 * wB.z;
            pr[k] = s0 * wA.y + s1 * wA.w + s2 * wB.y + s3 * wB.w;
        }
        #pragma unroll
        for (int off = 16; off > 0; off >>= 1)
            #pragma unroll
            for (int k = 0; k < 2; ++k) {
                pc[k] += __shfl_xor(pc[k], off, 64);
                pr[k] += __shfl_xor(pr[k], off, 64);
            }
        if (hq == 0) {
            float b2c = vdw_b2[0], b2r = vdw_b2[1];
            #pragma unroll
            for (int k = 0; k < 2; ++k) {
                int n = base + as + 4 * k;
                if (n < N) {
                    c6o[n] = softplus_f(pc[k] + b2c);
                    rvo[n] = softplus_f(pr[k] + b2r);
                }
            }
        }
    }

    // ---- mu: wave w handles atoms base+2w, base+2w+1; float2 loads + 6-step shuffle ----
    {
        int lane = tid & 63, wid = tid >> 6;
        float2 wm = ((const float2*)mu_w)[lane];
        #pragma unroll
        for (int r = 0; r < 2; ++r) {
            int n = base + wid * 2 + r;
            if (n < N) {                                  // wave-uniform
                const float2* row = (const float2*)(h1 + (size_t)n * 3 * F);
                float2 v0 = row[lane], v1 = row[64 + lane], v2 = row[128 + lane];
                float p0 = v0.x * wm.x + v0.y * wm.y;
                float p1 = v1.x * wm.x + v1.y * wm.y;
                float p2 = v2.x * wm.x + v2.y * wm.y;
                #pragma unroll
                for (int off = 1; off < 64; off <<= 1) {
                    p0 += __shfl_xor(p0, off, 64);
                    p1 += __shfl_xor(p1, off, 64);
                    p2 += __shfl_xor(p2, off, 64);
                }
                if (lane == 0) {
                    muo[n * 3 + 0] = p0;
                    muo[n * 3 + 1] = p1;
                    muo[n * 3 + 2] = p2;
                }
            }
        }
    }

    // ---- block 0: segment scan + ticket init (overlaps other 767 blocks; read next dispatch) ----
    if (blockIdx.x == 0) {
        if (tid < NSEG) {
            int s = tid;
            int lo = 0, hi = N;
            while (lo < hi) { int mid = (lo + hi) >> 1; if (batch[mid] < s) lo = mid + 1; else hi = mid; }
            int lo2 = lo, hi2 = N;
            while (lo2 < hi2) { int mid = (lo2 + hi2) >> 1; if (batch[mid] < s + 1) lo2 = mid + 1; else hi2 = mid; }
            seg_start[s] = lo;
            seg_cnt[s]   = lo2 - lo;
        } else if (tid == 64) {
            *ticket = 0;                  // ws is poisoned each launch; kernel-end flush publishes
        }
    }
}

// ---------------- Kernel 2: per-segment pairwise energy + last-block final reduce ----------------
template <bool USE_LDS>
__device__ float seg_energy_loop(int start, unsigned ns, unsigned chunk, float mn,
    float inv_s2s, float inv_sig,
    const float* __restrict__ pos, const float* __restrict__ qr,
    const float* __restrict__ c6a, const float* __restrict__ rva,
    const float* __restrict__ mua,
    const float* spos, const float* smu,
    const float* sq, const float* sc, const float* sr)
{
    float e = 0.0f;
    unsigned total = ns * ns;
    unsigned stride = SPLIT * 256u;
    unsigned p = chunk * 256u + threadIdx.x;
    if (p >= total) return 0.0f;
    unsigned i = p / ns;
    unsigned j = p - i * ns;
    unsigned di = stride / ns;
    unsigned dj = stride - di * ns;
    while (i < ns) {
        if (i != j) {
            float xi, yi, zi, qi, ci, ri, mxi, myi, mzi;
            float xj, yj, zj, qj, cj, rj, mxj, myj, mzj;
            if constexpr (USE_LDS) {
                xi = spos[3 * i]; yi = spos[3 * i + 1]; zi = spos[3 * i + 2];
                qi = sq[i]; ci = sc[i]; ri = sr[i];
                mxi = smu[3 * i]; myi = smu[3 * i + 1]; mzi = smu[3 * i + 2];
                xj = spos[3 * j]; yj = spos[3 * j + 1]; zj = spos[3 * j + 2];
                qj = sq[j]; cj = sc[j]; rj = sr[j];
                mxj = smu[3 * j]; myj = smu[3 * j + 1]; mzj = smu[3 * j + 2];
            } else {
                int gi = start + (int)i, gj = start + (int)j;
                xi = pos[gi * 3]; yi = pos[gi * 3 + 1]; zi = pos[gi * 3 + 2];
                qi = qr[gi] - mn; ci = c6a[gi]; ri = rva[gi];
                mxi = mua[gi * 3]; myi = mua[gi * 3 + 1]; mzi = mua[gi * 3 + 2];
                xj = pos[gj * 3]; yj = pos[gj * 3 + 1]; zj = pos[gj * 3 + 2];
                qj = qr[gj] - mn; cj = c6a[gj]; rj = rva[gj];
                mxj = mua[gj * 3]; myj = mua[gj * 3 + 1]; mzj = mua[gj * 3 + 2];
            }
            float dx = xi - xj, dy = yi - yj, dz = zi - zj;
            float d2 = dx * dx + dy * dy + dz * dz;
            float dist = sqrtf(d2 + 1e-8f);
            float inv = 1.0f / dist;
            // shielded Coulomb
            e += 0.5f * KE * qi * qj * inv * erff(dist * inv_s2s);
            // damped London dispersion: rv_ij^6 == (rv_i*rv_j)^3
            float c6ij = sqrtf(ci * cj);
            float rr = ri * rj;
            float damp = d2 * d2 * d2 + rr * rr * rr;
            e -= 0.5f * c6ij / damp;
            // dipole-dipole
            float nx = dx * inv, ny = dy * inv, nz = dz * inv;
            float mdm = mxi * mxj + myi * myj + mzi * mzj;
            float a1 = mxi * nx + myi * ny + mzi * nz;
            float a2 = mxj * nx + myj * ny + mzj * nz;
            float er = erff(dist * inv_sig);
            float rad = inv * inv * inv * er * er * er;
            e += 0.5f * KE * (mdm - 3.0f * a1 * a2) * rad;
        }
        i += di; j += dj;
        if (j >= ns) { j -= ns; ++i; }
    }
    return e;
}

__global__ __launch_bounds__(256) void pair_kernel(
    const float* __restrict__ pos, const float* __restrict__ qr,
    const float* __restrict__ c6a, const float* __restrict__ rva,
    const float* __restrict__ mua,
    const int* __restrict__ seg_start, const int* __restrict__ seg_cnt,
    const float* __restrict__ sigma_p, float* __restrict__ pairpart,
    int* __restrict__ ticket, float* __restrict__ out)
{
    __shared__ float spos[3 * CAP], smu[3 * CAP], sq[CAP], sc[CAP], sr[CAP];
    __shared__ float red[4];
    __shared__ float s_mean;
    __shared__ int   s_last;
    const int tid = threadIdx.x;
    int s = blockIdx.x & (NSEG - 1);
    unsigned chunk = (unsigned)blockIdx.x >> 6;
    int start = seg_start[s];
    int ns = seg_cnt[s];
    float e = 0.0f;
    if (ns >= 2) {
        float sig = sigma_p[0];
        float inv_s2s = 1.0f / (1.41421356237f * sig);
        float inv_sig = 1.0f / sig;
        bool use_lds = (ns <= CAP);            // block-uniform
        float mn = 0.0f;
        if (use_lds) {
            // coalesced flat staging (pos/mu contiguous per segment)
            for (int jj = tid; jj < 3 * ns; jj += 256) {
                spos[jj] = pos[3 * start + jj];
                smu[jj]  = mua[3 * start + jj];
            }
            for (int jj = tid; jj < ns; jj += 256) {
                sq[jj] = qr[start + jj];
                sc[jj] = c6a[start + jj];
                sr[jj] = rva[start + jj];
            }
            __syncthreads();
            // block-level mean of q
            float ms = 0.0f;
            for (int jj = tid; jj < ns; jj += 256) ms += sq[jj];
            #pragma unroll
            for (int off = 32; off > 0; off >>= 1) ms += __shfl_xor(ms, off, 64);
            if ((tid & 63) == 0) red[tid >> 6] = ms;
            __syncthreads();
            if (tid == 0) s_mean = (red[0] + red[1] + red[2] + red[3]) / (float)ns;
            __syncthreads();
            float m = s_mean;
            for (int jj = tid; jj < ns; jj += 256) sq[jj] -= m;
            __syncthreads();
            e = seg_energy_loop<true >(start, (unsigned)ns, chunk, mn, inv_s2s, inv_sig,
                                       pos, qr, c6a, rva, mua, spos, smu, sq, sc, sr);
        } else {
            float ms = 0.0f;
            for (int jj = tid; jj < ns; jj += 256) ms += qr[start + jj];
            #pragma unroll
            for (int off = 32; off > 0; off >>= 1) ms += __shfl_xor(ms, off, 64);
            if ((tid & 63) == 0) red[tid >> 6] = ms;
            __syncthreads();
            if (tid == 0) s_mean = (red[0] + red[1] + red[2] + red[3]) / (float)ns;
            __syncthreads();
            mn = s_mean;
            e = seg_energy_loop<false>(start, (unsigned)ns, chunk, mn, inv_s2s, inv_sig,
                                       pos, qr, c6a, rva, mua, spos, smu, sq, sc, sr);
        }
    }
    // block reduction -> one partial per block
    #pragma unroll
    for (int off = 32; off > 0; off >>= 1) e += __shfl_xor(e, off, 64);
    __shared__ float wsum[4];
    if ((tid & 63) == 0) wsum[tid >> 6] = e;
    __syncthreads();
    if (tid == 0) {
        pairpart[blockIdx.x] = wsum[0] + wsum[1] + wsum[2] + wsum[3];
        __threadfence();                       // release partial (device scope)
        int t = atomicAdd(ticket, 1);          // device-scope by default
        s_last = (t == NPAIRBLK - 1) ? 1 : 0;
    }
    __syncthreads();

    // opportunistic last block: reduce all partials -> out
    if (s_last) {
        __threadfence();                       // acquire others' partials
        float f = 0.0f;
        for (int i = tid; i < NPAIRBLK; i += 256) f += pairpart[i];
        #pragma unroll
        for (int off = 32; off > 0; off >>= 1) f += __shfl_xor(f, off, 64);
        if ((tid & 63) == 0) red[tid >> 6] = f;
        __syncthreads();
        if (tid == 0) out[0] = red[0] + red[1] + red[2] + red[3];
    }
}

extern "C" void kernel_launch(void* const* d_in, const int* in_sizes, int n_in,
                              void* d_out, int out_size, void* d_ws, size_t ws_size,
                              hipStream_t stream) {
    const float* h0     = (const float*)d_in[0];
    const float* h1     = (const float*)d_in[1];
    const float* pos    = (const float*)d_in[2];
    const int*   batch  = (const int*)d_in[3];
    const float* q_w1   = (const float*)d_in[4];
    const float* q_b1   = (const float*)d_in[5];
    const float* q_w2   = (const float*)d_in[6];
    const float* sigma  = (const float*)d_in[7];
    const float* vdw_w1 = (const float*)d_in[8];
    const float* vdw_b1 = (const float*)d_in[9];
    const float* vdw_w2 = (const float*)d_in[10];
    const float* vdw_b2 = (const float*)d_in[11];
    const float* mu_w   = (const float*)d_in[12];

    int N = in_sizes[0] / F;

    float* ws     = (float*)d_ws;
    float* q_raw  = ws;
    float* c6     = ws + (size_t)N;
    float* rv     = ws + (size_t)2 * N;
    float* mu     = ws + (size_t)3 * N;          // 3N floats
    int*   sstart = (int*)(ws + (size_t)6 * N);  // 64
    int*   scnt   = sstart + NSEG;               // 64
    float* ppart  = (float*)(scnt + NSEG);       // NPAIRBLK
    int*   ticket = (int*)(ppart + NPAIRBLK);    // 1

    int blocksA = (N + TA - 1) / TA;
    mlp_kernel<<<blocksA, 256, 0, stream>>>(h0, h1, batch,
        q_w1, q_b1, q_w2, vdw_w1, vdw_b1, vdw_w2, vdw_b2, mu_w,
        q_raw, c6, rv, mu, sstart, scnt, ticket, N);

    pair_kernel<<<NPAIRBLK, 256, 0, stream>>>(pos, q_raw, c6, rv, mu,
        sstart, scnt, sigma, ppart, ticket, (float*)d_out);
}

// Round 7
// 116.905 us; speedup vs baseline: 2.0202x; 1.0053x over previous
//
#include <hip/hip_runtime.h>

#define F 128
#define TA 8          // atoms per mlp block
#define NSEG 64
#define CAP 256       // max atoms per segment staged in LDS (seg avg ~96)
#define SPLIT 4       // blocks per segment in pair kernel (256 blocks = 1/CU)
#define NPAIRBLK (NSEG * SPLIT)
#define KE 14.3996f

__device__ __forceinline__ float silu_f(float x) {
    return x / (1.0f + expf(-x));
}
__device__ __forceinline__ float softplus_f(float x) {
    return fmaxf(x, 0.0f) + log1pf(expf(-fabsf(x)));
}

// ---------------- Kernel 1: per-atom MLPs (q, c6, rv) + mu + seg scan + ticket init ----------------
// 256 threads. m=tid>>7 picks MLP (0=q, 1=vdw). hq=tid&31 owns hidden units 4hq..4hq+3.
// as=(tid>>5)&3 owns atoms {as, as+4}. Weight loads software-pipelined one 4-f group ahead.
__global__ __launch_bounds__(256) void mlp_kernel(
    const float* __restrict__ h0, const float* __restrict__ h1,
    const int* __restrict__ batch,
    const float* __restrict__ q_w1, const float* __restrict__ q_b1, const float* __restrict__ q_w2,
    const float* __restrict__ vdw_w1, const float* __restrict__ vdw_b1,
    const float* __restrict__ vdw_w2, const float* __restrict__ vdw_b2,
    const float* __restrict__ mu_w,
    float* __restrict__ q_raw, float* __restrict__ c6o, float* __restrict__ rvo,
    float* __restrict__ muo, int* __restrict__ seg_start, int* __restrict__ seg_cnt,
    int* __restrict__ ticket, int N)
{
    __shared__ float h0s[TA][F];          // 4 KB
    const int tid = threadIdx.x;
    const int m  = tid >> 7;              // wave-uniform (waves 0,1 -> q; 2,3 -> vdw)
    const int hq = tid & 31;
    const int as = (tid >> 5) & 3;
    const int base = blockIdx.x * TA;

    // ---- stage h0 tile: 8 atoms x 128 floats = 256 float4, one per thread ----
    {
        const float4* src = (const float4*)(h0 + (size_t)base * F);
        int a = tid >> 5;
        ((float4*)&h0s[0][0])[tid] =
            (base + a < N) ? src[tid] : make_float4(0.f, 0.f, 0.f, 0.f);
    }
    __syncthreads();

    // ---- layer 1: acc[k][j] = sum_f h0[atom][f] * W1[f][4hq+j], atoms {as, as+4} ----
    // scalar broadcast LDS reads (free at <=2 addrs/wave); weights prefetched 1 group ahead.
    const float4* __restrict__ Wp = (const float4*)(m ? vdw_w1 : q_w1) + hq;
    float acc[2][4];
    #pragma unroll
    for (int k = 0; k < 2; ++k)
        #pragma unroll
        for (int j = 0; j < 4; ++j) acc[k][j] = 0.0f;

    float4 wv[4];
    #pragma unroll
    for (int c = 0; c < 4; ++c) wv[c] = Wp[c * 32];

    for (int f0 = 0; f0 < F; f0 += 4) {
        // prefetch next group (clamped on last iteration; stays in-buffer)
        int fn = (f0 + 4 < F) ? (f0 + 4) : f0;
        float4 wn[4];
        #pragma unroll
        for (int c = 0; c < 4; ++c) wn[c] = Wp[(fn + c) * 32];
        #pragma unroll
        for (int c = 0; c < 4; ++c) {
            float ha = h0s[as][f0 + c];          // wave-broadcast scalar LDS reads
            float hb = h0s[as + 4][f0 + c];
            acc[0][0] = fmaf(ha, wv[c].x, acc[0][0]);
            acc[0][1] = fmaf(ha, wv[c].y, acc[0][1]);
            acc[0][2] = fmaf(ha, wv[c].z, acc[0][2]);
            acc[0][3] = fmaf(ha, wv[c].w, acc[0][3]);
            acc[1][0] = fmaf(hb, wv[c].x, acc[1][0]);
            acc[1][1] = fmaf(hb, wv[c].y, acc[1][1]);
            acc[1][2] = fmaf(hb, wv[c].z, acc[1][2]);
            acc[1][3] = fmaf(hb, wv[c].w, acc[1][3]);
        }
        #pragma unroll
        for (int c = 0; c < 4; ++c) wv[c] = wn[c];
    }

    // ---- activation + layer 2 + 32-lane reduction ----
    if (m == 0) {
        float4 b  = ((const float4*)q_b1)[hq];
        float4 w2 = ((const float4*)q_w2)[hq];
        float part[2];
        #pragma unroll
        for (int k = 0; k < 2; ++k) {
            part[k] = silu_f(acc[k][0] + b.x) * w2.x
                    + silu_f(acc[k][1] + b.y) * w2.y
                    + silu_f(acc[k][2] + b.z) * w2.z
                    + silu_f(acc[k][3] + b.w) * w2.w;
        }
        #pragma unroll
        for (int off = 16; off > 0; off >>= 1)
            #pragma unroll
            for (int k = 0; k < 2; ++k)
                part[k] += __shfl_xor(part[k], off, 64);
        if (hq == 0) {
            #pragma unroll
            for (int k = 0; k < 2; ++k) {
                int n = base + as + 4 * k;
                if (n < N) q_raw[n] = part[k];
            }
        }
    } else {
        float4 b  = ((const float4*)vdw_b1)[hq];
        float4 wA = ((const float4*)vdw_w2)[2 * hq];      // (c6w,rvw) for units 4hq,4hq+1
        float4 wB = ((const float4*)vdw_w2)[2 * hq + 1];  // units 4hq+2,4hq+3
        float pc[2], pr[2];
        #pragma unroll
        for (int k = 0; k < 2; ++k) {
            float s0 = silu_f(acc[k][0] + b.x);
            float s1 = silu_f(acc[k][1] + b.y);
            float s2 = silu_f(acc[k][2] + b.z);
            float s3 = silu_f(acc[k][3] + b.w);
            pc[k] = s0 * wA.x + s1 * wA.z + s2 * wB.x + s3 * wB.z;
            pr[k] = s0 * wA.y + s1 * wA.w + s2 * wB.y + s3 * wB.w;
        }
        #pragma unroll
        for (int off = 16; off > 0; off >>= 1)
            #pragma unroll
            for (int k = 0; k < 2; ++k) {
                pc[k] += __shfl_xor(pc[k], off, 64);
                pr[k] += __shfl_xor(pr[k], off, 64);
            }
        if (hq == 0) {
            float b2c = vdw_b2[0], b2r = vdw_b2[1];
            #pragma unroll
            for (int k = 0; k < 2; ++k) {
                int n = base + as + 4 * k;
                if (n < N) {
                    c6o[n] = softplus_f(pc[k] + b2c);
                    rvo[n] = softplus_f(pr[k] + b2r);
                }
            }
        }
    }

    // ---- mu: wave w handles atoms base+2w, base+2w+1; float2 loads + 6-step shuffle ----
    {
        int lane = tid & 63, wid = tid >> 6;
        float2 wm = ((const float2*)mu_w)[lane];
        #pragma unroll
        for (int r = 0; r < 2; ++r) {
            int n = base + wid * 2 + r;
            if (n < N) {                                  // wave-uniform
                const float2* row = (const float2*)(h1 + (size_t)n * 3 * F);
                float2 v0 = row[lane], v1 = row[64 + lane], v2 = row[128 + lane];
                float p0 = v0.x * wm.x + v0.y * wm.y;
                float p1 = v1.x * wm.x + v1.y * wm.y;
                float p2 = v2.x * wm.x + v2.y * wm.y;
                #pragma unroll
                for (int off = 1; off < 64; off <<= 1) {
                    p0 += __shfl_xor(p0, off, 64);
                    p1 += __shfl_xor(p1, off, 64);
                    p2 += __shfl_xor(p2, off, 64);
                }
                if (lane == 0) {
                    muo[n * 3 + 0] = p0;
                    muo[n * 3 + 1] = p1;
                    muo[n * 3 + 2] = p2;
                }
            }
        }
    }

    // ---- block 0: segment scan + ticket init (overlaps other 767 blocks; read next dispatch) ----
    if (blockIdx.x == 0) {
        if (tid < NSEG) {
            int s = tid;
            int lo = 0, hi = N;
            while (lo < hi) { int mid = (lo + hi) >> 1; if (batch[mid] < s) lo = mid + 1; else hi = mid; }
            int lo2 = lo, hi2 = N;
            while (lo2 < hi2) { int mid = (lo2 + hi2) >> 1; if (batch[mid] < s + 1) lo2 = mid + 1; else hi2 = mid; }
            seg_start[s] = lo;
            seg_cnt[s]   = lo2 - lo;
        } else if (tid == 64) {
            *ticket = 0;                  // ws is poisoned each launch; kernel-end flush publishes
        }
    }
}

// ---------------- Kernel 2: per-segment pairwise energy + last-block final reduce ----------------
template <bool USE_LDS>
__device__ float seg_energy_loop(int start, unsigned ns, unsigned chunk, float mn,
    float inv_s2s, float inv_sig,
    const float* __restrict__ pos, const float* __restrict__ qr,
    const float* __restrict__ c6a, const float* __restrict__ rva,
    const float* __restrict__ mua,
    const float* spos, const float* smu,
    const float* sq, const float* sc, const float* sr)
{
    float e = 0.0f;
    unsigned total = ns * ns;
    unsigned stride = SPLIT * 256u;
    unsigned p = chunk * 256u + threadIdx.x;
    if (p >= total) return 0.0f;
    unsigned i = p / ns;
    unsigned j = p - i * ns;
    unsigned di = stride / ns;
    unsigned dj = stride - di * ns;
    while (i < ns) {
        if (i != j) {
            float xi, yi, zi, qi, ci, ri, mxi, myi, mzi;
            float xj, yj, zj, qj, cj, rj, mxj, myj, mzj;
            if constexpr (USE_LDS) {
                xi = spos[3 * i]; yi = spos[3 * i + 1]; zi = spos[3 * i + 2];
                qi = sq[i]; ci = sc[i]; ri = sr[i];
                mxi = smu[3 * i]; myi = smu[3 * i + 1]; mzi = smu[3 * i + 2];
                xj = spos[3 * j]; yj = spos[3 * j + 1]; zj = spos[3 * j + 2];
                qj = sq[j]; cj = sc[j]; rj = sr[j];
                mxj = smu[3 * j]; myj = smu[3 * j + 1]; mzj = smu[3 * j + 2];
            } else {
                int gi = start + (int)i, gj = start + (int)j;
                xi = pos[gi * 3]; yi = pos[gi * 3 + 1]; zi = pos[gi * 3 + 2];
                qi = qr[gi] - mn; ci = c6a[gi]; ri = rva[gi];
                mxi = mua[gi * 3]; myi = mua[gi * 3 + 1]; mzi = mua[gi * 3 + 2];
                xj = pos[gj * 3]; yj = pos[gj * 3 + 1]; zj = pos[gj * 3 + 2];
                qj = qr[gj] - mn; cj = c6a[gj]; rj = rva[gj];
                mxj = mua[gj * 3]; myj = mua[gj * 3 + 1]; mzj = mua[gj * 3 + 2];
            }
            float dx = xi - xj, dy = yi - yj, dz = zi - zj;
            float d2 = dx * dx + dy * dy + dz * dz;
            float dist = sqrtf(d2 + 1e-8f);
            float inv = 1.0f / dist;
            // shielded Coulomb
            e += 0.5f * KE * qi * qj * inv * erff(dist * inv_s2s);
            // damped London dispersion: rv_ij^6 == (rv_i*rv_j)^3
            float c6ij = sqrtf(ci * cj);
            float rr = ri * rj;
            float damp = d2 * d2 * d2 + rr * rr * rr;
            e -= 0.5f * c6ij / damp;
            // dipole-dipole
            float nx = dx * inv, ny = dy * inv, nz = dz * inv;
            float mdm = mxi * mxj + myi * myj + mzi * mzj;
            float a1 = mxi * nx + myi * ny + mzi * nz;
            float a2 = mxj * nx + myj * ny + mzj * nz;
            float er = erff(dist * inv_sig);
            float rad = inv * inv * inv * er * er * er;
            e += 0.5f * KE * (mdm - 3.0f * a1 * a2) * rad;
        }
        i += di; j += dj;
        if (j >= ns) { j -= ns; ++i; }
    }
    return e;
}

__global__ __launch_bounds__(256) void pair_kernel(
    const float* __restrict__ pos, const float* __restrict__ qr,
    const float* __restrict__ c6a, const float* __restrict__ rva,
    const float* __restrict__ mua,
    const int* __restrict__ seg_start, const int* __restrict__ seg_cnt,
    const float* __restrict__ sigma_p, float* __restrict__ pairpart,
    int* __restrict__ ticket, float* __restrict__ out)
{
    __shared__ float spos[3 * CAP], smu[3 * CAP], sq[CAP], sc[CAP], sr[CAP];
    __shared__ float red[4];
    __shared__ float s_mean;
    __shared__ int   s_last;
    const int tid = threadIdx.x;
    int s = blockIdx.x & (NSEG - 1);
    unsigned chunk = (unsigned)blockIdx.x >> 6;
    int start = seg_start[s];
    int ns = seg_cnt[s];
    float e = 0.0f;
    if (ns >= 2) {
        float sig = sigma_p[0];
        float inv_s2s = 1.0f / (1.41421356237f * sig);
        float inv_sig = 1.0f / sig;
        bool use_lds = (ns <= CAP);            // block-uniform
        float mn = 0.0f;
        if (use_lds) {
            // coalesced flat staging (pos/mu contiguous per segment)
            for (int jj = tid; jj < 3 * ns; jj += 256) {
                spos[jj] = pos[3 * start + jj];
                smu[jj]  = mua[3 * start + jj];
            }
            for (int jj = tid; jj < ns; jj += 256) {
                sq[jj] = qr[start + jj];
                sc[jj] = c6a[start + jj];
                sr[jj] = rva[start + jj];
            }
            __syncthreads();
            // block-level mean of q
            float ms = 0.0f;
            for (int jj = tid; jj < ns; jj += 256) ms += sq[jj];
            #pragma unroll
            for (int off = 32; off > 0; off >>= 1) ms += __shfl_xor(ms, off, 64);
            if ((tid & 63) == 0) red[tid >> 6] = ms;
            __syncthreads();
            if (tid == 0) s_mean = (red[0] + red[1] + red[2] + red[3]) / (float)ns;
            __syncthreads();
            float m = s_mean;
            for (int jj = tid; jj < ns; jj += 256) sq[jj] -= m;
            __syncthreads();
            e = seg_energy_loop<true >(start, (unsigned)ns, chunk, mn, inv_s2s, inv_sig,
                                       pos, qr, c6a, rva, mua, spos, smu, sq, sc, sr);
        } else {
            float ms = 0.0f;
            for (int jj = tid; jj < ns; jj += 256) ms += qr[start + jj];
            #pragma unroll
            for (int off = 32; off > 0; off >>= 1) ms += __shfl_xor(ms, off, 64);
            if ((tid & 63) == 0) red[tid >> 6] = ms;
            __syncthreads();
            if (tid == 0) s_mean = (red[0] + red[1] + red[2] + red[3]) / (float)ns;
            __syncthreads();
            mn = s_mean;
            e = seg_energy_loop<false>(start, (unsigned)ns, chunk, mn, inv_s2s, inv_sig,
                                       pos, qr, c6a, rva, mua, spos, smu, sq, sc, sr);
        }
    }
    // block reduction -> one partial per block
    #pragma unroll
    for (int off = 32; off > 0; off >>= 1) e += __shfl_xor(e, off, 64);
    __shared__ float wsum[4];
    if ((tid & 63) == 0) wsum[tid >> 6] = e;
    __syncthreads();
    if (tid == 0) {
        pairpart[blockIdx.x] = wsum[0] + wsum[1] + wsum[2] + wsum[3];
        __threadfence();                       // release partial (device scope)
        int t = atomicAdd(ticket, 1);          // device-scope by default
        s_last = (t == NPAIRBLK - 1) ? 1 : 0;
    }
    __syncthreads();

    // opportunistic last block: reduce all partials -> out
    if (s_last) {
        __threadfence();                       // acquire others' partials
        float f = 0.0f;
        for (int i = tid; i < NPAIRBLK; i += 256) f += pairpart[i];
        #pragma unroll
        for (int off = 32; off > 0; off >>= 1) f += __shfl_xor(f, off, 64);
        if ((tid & 63) == 0) red[tid >> 6] = f;
        __syncthreads();
        if (tid == 0) out[0] = red[0] + red[1] + red[2] + red[3];
    }
}

extern "C" void kernel_launch(void* const* d_in, const int* in_sizes, int n_in,
                              void* d_out, int out_size, void* d_ws, size_t ws_size,
                              hipStream_t stream) {
    const float* h0     = (const float*)d_in[0];
    const float* h1     = (const float*)d_in[1];
    const float* pos    = (const float*)d_in[2];
    const int*   batch  = (const int*)d_in[3];
    const float* q_w1   = (const float*)d_in[4];
    const float* q_b1   = (const float*)d_in[5];
    const float* q_w2   = (const float*)d_in[6];
    const float* sigma  = (const float*)d_in[7];
    const float* vdw_w1 = (const float*)d_in[8];
    const float* vdw_b1 = (const float*)d_in[9];
    const float* vdw_w2 = (const float*)d_in[10];
    const float* vdw_b2 = (const float*)d_in[11];
    const float* mu_w   = (const float*)d_in[12];

    int N = in_sizes[0] / F;

    float* ws     = (float*)d_ws;
    float* q_raw  = ws;
    float* c6     = ws + (size_t)N;
    float* rv     = ws + (size_t)2 * N;
    float* mu     = ws + (size_t)3 * N;          // 3N floats
    int*   sstart = (int*)(ws + (size_t)6 * N);  // 64
    int*   scnt   = sstart + NSEG;               // 64
    float* ppart  = (float*)(scnt + NSEG);       // NPAIRBLK
    int*   ticket = (int*)(ppart + NPAIRBLK);    // 1

    int blocksA = (N + TA - 1) / TA;
    mlp_kernel<<<blocksA, 256, 0, stream>>>(h0, h1, batch,
        q_w1, q_b1, q_w2, vdw_w1, vdw_b1, vdw_w2, vdw_b2, mu_w,
        q_raw, c6, rv, mu, sstart, scnt, ticket, N);

    pair_kernel<<<NPAIRBLK, 256, 0, stream>>>(pos, q_raw, c6, rv, mu,
        sstart, scnt, sigma, ppart, ticket, (float*)d_out);
}